// Round 3
// baseline (419.035 us; speedup 1.0000x reference)
//
#include <hip/hip_runtime.h>
#include <hip/hip_bf16.h>
#include <stdint.h>

// ---- problem constants ----
#define N_IMG 32
#define C_IN  256
#define HW    56
#define PIX   3136            // 56*56
#define M_TOT 100352          // 32*3136
#define C_OUT 256
#define K_TOT 2304            // 256*9
#define HP    58
#define WPAD  58
#define OUT_IMG_STRIDE 802816 // 256*3136

// ---- tile config: BM=224 (4 image rows), BN=128, slab-reuse over 9 taps ----
#define BM 224
#define BN 128
#define SLAB_PX 348           // 6 padded rows * 58 cols

typedef __attribute__((ext_vector_type(8))) short bf16x8_t;   // 8 bf16 = 4 VGPRs
typedef __attribute__((ext_vector_type(4))) float f32x4_t;

// ---------------- pass 0: zero only the padded border -------------------------------
__global__ void border_zero_kernel(__hip_bfloat16* __restrict__ xpad) {
    int t = blockIdx.x * 256 + threadIdx.x;   // 32 n * 228 border px * 32 uint4
    if (t >= 32 * 228 * 32) return;
    int n = t / (228 * 32);
    int r = t - n * (228 * 32);
    int px = r >> 5, part = r & 31;
    int hp, wp;
    if (px < 58)       { hp = 0;  wp = px; }
    else if (px < 116) { hp = 57; wp = px - 116 + 58; }
    else { int k = px - 116; hp = 1 + (k >> 1); wp = (k & 1) ? 57 : 0; }
    long e = (((long)n * HP + hp) * WPAD + wp) * C_IN + part * 8;
    *(uint4*)(xpad + e) = make_uint4(0u, 0u, 0u, 0u);
}

// ---------------- pass 1: NCHW fp32 -> padded NHWC bf16 transpose --------------------
__global__ void xform_kernel(const float* __restrict__ x, __hip_bfloat16* __restrict__ xpad) {
    __shared__ float tile[64][65];
    int b   = blockIdx.x;
    int n   = b / 196;
    int rem = b - n * 196;
    int ct  = rem / 49;
    int pt  = rem - ct * 49;
    int c0 = ct * 64, p0 = pt * 64;
    int t = threadIdx.x;

    const float* xs = x + (size_t)n * C_IN * PIX;
    int pc = t & 63, cr = t >> 6;   // read: coalesced along pixels (256 B/wave-instr)
#pragma unroll
    for (int it = 0; it < 16; ++it) {
        int c = c0 + it * 4 + cr;
        tile[it * 4 + cr][pc] = xs[(size_t)c * PIX + p0 + pc];
    }
    __syncthreads();
    // write: 4 chans/lane, ushort4 (8 B) stores -> 128 B contiguous per 16 lanes
    int l = t & 63, wv = t >> 6;
    int mq = l & 15, pxw = l >> 4;
#pragma unroll
    for (int it = 0; it < 4; ++it) {
        int px = it * 16 + wv * 4 + pxw;    // 0..63
        int gp = p0 + px;
        int h = gp / 56, w = gp - h * 56;
        // banks (65*(4mq+k)+px)%32 = (4mq+k+px)%32: fixed k -> 2-way (free)
        float f0 = tile[4 * mq + 0][px];
        float f1 = tile[4 * mq + 1][px];
        float f2 = tile[4 * mq + 2][px];
        float f3 = tile[4 * mq + 3][px];
        __hip_bfloat16 b0 = __float2bfloat16(f0), b1 = __float2bfloat16(f1);
        __hip_bfloat16 b2 = __float2bfloat16(f2), b3 = __float2bfloat16(f3);
        ushort4 v;
        v.x = *(unsigned short*)&b0; v.y = *(unsigned short*)&b1;
        v.z = *(unsigned short*)&b2; v.w = *(unsigned short*)&b3;
        *(ushort4*)&xpad[(((size_t)n * HP + h + 1) * WPAD + (w + 1)) * C_IN + c0 + 4 * mq] = v;
    }
}

// ---------------- pass 2: binarize + transpose weights -> wt[cout][tap][c] bf16 -------
__global__ void wxform_kernel(const float* __restrict__ w, __hip_bfloat16* __restrict__ wt) {
    int i = blockIdx.x * 256 + threadIdx.x;   // over 589824
    if (i >= C_OUT * K_TOT) return;
    int cout = i / K_TOT;
    int r    = i - cout * K_TOT;
    int tap  = r >> 8;
    int c    = r & 255;
    float v = w[cout * 2304 + c * 9 + tap];   // [cout][cin][3][3]
    float s = (v > 0.f) ? 1.f : ((v < 0.f) ? -1.f : 0.f);
    wt[i] = __float2bfloat16(s);
}

// ---------------- pass 3: slab-reuse implicit-GEMM, async double-buffered ------------
__device__ __forceinline__ void gload_lds16(const __hip_bfloat16* g, __hip_bfloat16* l) {
    __builtin_amdgcn_global_load_lds(
        (const __attribute__((address_space(1))) void*)g,
        (__attribute__((address_space(3))) void*)l, 16, 0, 0);
}

__global__ void __launch_bounds__(256, 2)
gemm_kernel(const __hip_bfloat16* __restrict__ xpad,
            const __hip_bfloat16* __restrict__ wt,
            const float* __restrict__ bias,
            float* __restrict__ out) {
    // packed slab: [pp][part'] with part' = (chan_part + (pp>>1)) & 3 swizzle
    __shared__ __hip_bfloat16 slab[2][SLAB_PX * 32];   // 2 x 22272 B

    int bx = blockIdx.x;                 // 896 blocks; bx and bx+8 share an XCD
    int g = bx >> 4, xg = bx & 7, nt = (bx >> 3) & 1;
    int mt = g * 8 + xg;                 // 0..447
    int nimg = mt / 14, ti = mt - nimg * 14;
    int r0 = ti * 4;
    int n0 = nt * BN;

    int tid = threadIdx.x, lane = tid & 63, wv = tid >> 6;
    int wm = wv >> 1, wn = wv & 1;
    int ar = lane & 15, kq = lane >> 4;

    const __hip_bfloat16* winBase = xpad + ((long)(nimg * HP + r0) * WPAD) * C_IN;

    // staging: wave wv stages window pixels [wv*87, +87), 4x16B parts each.
    // slot s: pp = wv*87 + (s>>2), part' q = s&3 holds chan-part p = (q-(pp>>1))&3.
    long stgSrc[6]; bool stgAct[6];
#pragma unroll
    for (int i = 0; i < 6; ++i) {
        int s = i * 64 + lane;
        int pp = wv * 87 + (s >> 2);
        int p = ((s & 3) - (pp >> 1)) & 3;
        stgSrc[i] = (long)pp * C_IN + p * 8;     // element offset; +ch*32 per chunk
        stgAct[i] = (s < SLAB_PX);
    }

    // a-frag window-pixel index for tap(0,0): m = wm*112 + i*16 + ar
    int pp0[7];
#pragma unroll
    for (int i = 0; i < 7; ++i) {
        int m = wm * 112 + i * 16 + ar;
        int dr = m / 56, wc = m - dr * 56;
        pp0[i] = dr * 58 + wc;
    }
    const int TAP_PP[9] = {0, 1, 2, 58, 59, 60, 116, 117, 118};

    // B bases (elements into wt)
    long wb[4];
#pragma unroll
    for (int j = 0; j < 4; ++j)
        wb[j] = (long)(n0 + wn * 64 + j * 16 + ar) * K_TOT + kq * 8;

    f32x4_t acc[7][4] = {};

    // prologue: stage chunk 0, preload B(ch0,tap0)
#pragma unroll
    for (int i = 0; i < 6; ++i)
        if (stgAct[i]) gload_lds16(winBase + stgSrc[i], &slab[0][wv * 2784 + i * 512]);
    bf16x8_t bc[4];
#pragma unroll
    for (int j = 0; j < 4; ++j) bc[j] = *(const bf16x8_t*)(wt + wb[j]);
    __syncthreads();

    for (int ch = 0; ch < 8; ++ch) {
        const char* sl = (const char*)&slab[ch & 1][0];
        if (ch < 7) {   // async prefetch next chunk; drained by the barrier below
            __hip_bfloat16* d = &slab[(ch + 1) & 1][wv * 2784];
            long co = (long)(ch + 1) * 32;
#pragma unroll
            for (int i = 0; i < 6; ++i)
                if (stgAct[i]) gload_lds16(winBase + stgSrc[i] + co, d + i * 512);
        }
#pragma unroll
        for (int t = 0; t < 9; ++t) {
            // prefetch next tap's B (or next chunk's tap 0)
            bf16x8_t bn[4];
            int nk = (t < 8) ? ((t + 1) * 256 + ch * 32)
                             : ((ch < 7) ? (ch + 1) * 32 : 0);
#pragma unroll
            for (int j = 0; j < 4; ++j)
                bn[j] = *(const bf16x8_t*)(wt + wb[j] + nk);
            // a-frags from swizzled slab (2-way banks = free)
            bf16x8_t a[7];
            const int tpp = TAP_PP[t];
#pragma unroll
            for (int i = 0; i < 7; ++i) {
                int pp = pp0[i] + tpp;
                int off = pp * 64 + (((kq + (pp >> 1)) & 3) << 4);
                a[i] = *(const bf16x8_t*)(sl + off);
            }
#pragma unroll
            for (int i = 0; i < 7; ++i)
#pragma unroll
                for (int j = 0; j < 4; ++j)
                    acc[i][j] = __builtin_amdgcn_mfma_f32_16x16x32_bf16(a[i], bc[j], acc[i][j], 0, 0, 0);
#pragma unroll
            for (int j = 0; j < 4; ++j) bc[j] = bn[j];
        }
        __syncthreads();
    }

    // epilogue: C/D col=lane&15 (n), row=(lane>>4)*4+reg (m); float4 stores along m
    int cn = lane & 15;
    int rq = (lane >> 4) * 4;
    long outb = (long)nimg * OUT_IMG_STRIDE + r0 * 56;
#pragma unroll
    for (int i = 0; i < 7; ++i) {
        int mb = wm * 112 + i * 16 + rq;
#pragma unroll
        for (int j = 0; j < 4; ++j) {
            int cout = n0 + wn * 64 + j * 16 + cn;
            float bv = bias[cout];
            f32x4_t v = acc[i][j];
            v[0] += bv; v[1] += bv; v[2] += bv; v[3] += bv;
            *(f32x4_t*)&out[outb + (long)cout * PIX + mb] = v;
        }
    }
}

extern "C" void kernel_launch(void* const* d_in, const int* in_sizes, int n_in,
                              void* d_out, int out_size, void* d_ws, size_t ws_size,
                              hipStream_t stream) {
    const float* x    = (const float*)d_in[0];
    const float* wgt  = (const float*)d_in[1];
    const float* bias = (const float*)d_in[2];
    float* out = (float*)d_out;

    __hip_bfloat16* xpad = (__hip_bfloat16*)d_ws;                       // 55,115,776 B
    __hip_bfloat16* wt   = (__hip_bfloat16*)((char*)d_ws + 55115776);   // 1,179,648 B

    border_zero_kernel<<<dim3((32 * 228 * 32 + 255) / 256), dim3(256), 0, stream>>>(xpad);
    xform_kernel<<<dim3(N_IMG * 4 * 49), dim3(256), 0, stream>>>(x, xpad);
    wxform_kernel<<<dim3((C_OUT * K_TOT + 255) / 256), dim3(256), 0, stream>>>(wgt, wt);
    gemm_kernel<<<dim3((M_TOT / BM) * (C_OUT / BN)), dim3(256), 0, stream>>>(xpad, wt, bias, out);
}